// Round 1
// baseline (18399.342 us; speedup 1.0000x reference)
//
#include <hip/hip_runtime.h>
#include <cmath>

namespace {

constexpr int B  = 4096;
constexpr int H  = 1024;
constexpr int FH = 4 * H;   // 4096
constexpr int NSTEPS = 45;

__device__ __forceinline__ float sigf(float x) { return 1.0f / (1.0f + expf(-x)); }

// ---------------- one-time precompute of x-path tables ----------------
// tblD/tblR/tblK[s][j] = emb[s] @ W_ih.T (+ b_ih + b_hh folded)
// condp[i][j]          = cond_emb[i] @ W_ih[:, :512].T   (no bias)
// base0[j]             = sc_emb[sid] @ W_ih[:, 512:].T + b_ih + b_hh
__global__ void precompute_kernel(
    const float* __restrict__ W_ih, const float* __restrict__ b_ih, const float* __restrict__ b_hh,
    const float* __restrict__ depth_emb, const float* __restrict__ ratio_emb, const float* __restrict__ ks_emb,
    const float* __restrict__ cond_emb, const float* __restrict__ sc_emb, const int* __restrict__ sid_p,
    float* __restrict__ tblD, float* __restrict__ tblR, float* __restrict__ tblK,
    float* __restrict__ condp, float* __restrict__ base0) {
  int j = blockIdx.x * blockDim.x + threadIdx.x;
  if (j >= FH) return;
  const float* wr = W_ih + (size_t)j * H;
  float aD0=0,aD1=0,aD2=0,aR0=0,aR1=0,aR2=0,aK0=0,aK1=0,aK2=0;
  for (int k = 0; k < H; ++k) {
    float w = wr[k];
    aD0 += depth_emb[k]       * w;
    aD1 += depth_emb[H + k]   * w;
    aD2 += depth_emb[2*H + k] * w;
    aR0 += ratio_emb[k]       * w;
    aR1 += ratio_emb[H + k]   * w;
    aR2 += ratio_emb[2*H + k] * w;
    aK0 += ks_emb[k]          * w;
    aK1 += ks_emb[H + k]      * w;
    aK2 += ks_emb[2*H + k]    * w;
  }
  int sid = sid_p[0];
  constexpr int HH = H / 2;
  float a0=0,a1=0,a2=0,a3=0,a4=0,aS=0;
  for (int k = 0; k < HH; ++k) {
    float w = wr[k];
    a0 += cond_emb[0*HH + k] * w;
    a1 += cond_emb[1*HH + k] * w;
    a2 += cond_emb[2*HH + k] * w;
    a3 += cond_emb[3*HH + k] * w;
    a4 += cond_emb[4*HH + k] * w;
    aS += sc_emb[sid*HH + k] * wr[HH + k];
  }
  float bias = b_ih[j] + b_hh[j];
  tblD[0*FH+j]=aD0+bias; tblD[1*FH+j]=aD1+bias; tblD[2*FH+j]=aD2+bias;
  tblR[0*FH+j]=aR0+bias; tblR[1*FH+j]=aR1+bias; tblR[2*FH+j]=aR2+bias;
  tblK[0*FH+j]=aK0+bias; tblK[1*FH+j]=aK1+bias; tblK[2*FH+j]=aK2+bias;
  condp[0*FH+j]=a0; condp[1*FH+j]=a1; condp[2*FH+j]=a2; condp[3*FH+j]=a3; condp[4*FH+j]=a4;
  base0[j] = aS + bias;
}

// ---------------- step 0: h=c=0, gates = interp(x-path) only ----------------
__global__ void step0_kernel(const float* __restrict__ constraints,
                             const float* __restrict__ condp, const float* __restrict__ base0,
                             float* __restrict__ h, float* __restrict__ c) {
  int idx = blockIdx.x * blockDim.x + threadIdx.x;   // b*H + j
  int b = idx >> 10;
  int j = idx & (H - 1);
  float cv = constraints[b];
  // clist = [10, 12.5, 15, 17.5, 20]; searchsorted(right)-1, clipped
  int i0 = 0;
  if (cv >= 12.5f) i0 = 1;
  if (cv >= 15.0f) i0 = 2;
  if (cv >= 17.5f) i0 = 3;
  float right = 10.0f + 2.5f * (float)(i0 + 1);
  float w = (right - cv) / 2.5f;
  const float* c0 = condp + (size_t)i0 * FH;
  const float* c1 = c0 + FH;
  float iw = 1.0f - w;
  float xi = w*c0[j]       + iw*c1[j]       + base0[j];
  float xf = w*c0[H+j]     + iw*c1[H+j]     + base0[H+j];
  float xg = w*c0[2*H+j]   + iw*c1[2*H+j]   + base0[2*H+j];
  float xo = w*c0[3*H+j]   + iw*c1[3*H+j]   + base0[3*H+j];
  (void)xf;  // sigmoid(f)*c_prev with c_prev==0 contributes exactly 0
  float cn = sigf(xi) * tanhf(xg);
  float hn = sigf(xo) * tanhf(cn);
  c[idx] = cn;
  h[idx] = hn;
}

// ---------------- per-step: gates = tbl[sel[b]] + h @ W_hh.T, then LSTM cell ----------------
constexpr int BM = 128;  // batch tile
constexpr int BN = 64;   // hidden-j tile (x4 gates)
constexpr int BK = 32;

__global__ __launch_bounds__(256, 2) void lstm_step(
    const float* __restrict__ hin, float* __restrict__ hout,
    float* __restrict__ cbuf, const float* __restrict__ Whh,
    const float* __restrict__ tbl, const int* __restrict__ sel) {
  __shared__ float hs[BK][BM];        // 16 KB, transposed h tile
  __shared__ float wsb[4][BK][BN];    // 32 KB, transposed W tiles per gate
  int tid = threadIdx.x;
  int tx = tid & 15;       // n (j) group -> 4 cols
  int ty = tid >> 4;       // m (b) group -> 8 rows
  int b0 = blockIdx.y * BM;
  int j0 = blockIdx.x * BN;

  float acc[4][8][4] = {};

  int cc = (tid & 7) * 4;   // staging col (k) float4 base
  int r0 = tid >> 3;        // staging row 0..31

  for (int kt = 0; kt < H; kt += BK) {
    // stage h tile (128 rows x 32 k), transposed
    #pragma unroll
    for (int p = 0; p < 4; ++p) {
      int r = r0 + p * 32;
      float4 v = *(const float4*)(hin + (size_t)(b0 + r) * H + kt + cc);
      hs[cc+0][r] = v.x; hs[cc+1][r] = v.y; hs[cc+2][r] = v.z; hs[cc+3][r] = v.w;
    }
    // stage W tiles: 4 gates x 64 rows x 32 k, transposed
    #pragma unroll
    for (int p = 0; p < 8; ++p) {
      int row = r0 + p * 32;          // 0..255
      int g  = row >> 6;
      int jr = row & 63;
      float4 v = *(const float4*)(Whh + (size_t)(g * H + j0 + jr) * H + kt + cc);
      wsb[g][cc+0][jr] = v.x; wsb[g][cc+1][jr] = v.y; wsb[g][cc+2][jr] = v.z; wsb[g][cc+3][jr] = v.w;
    }
    __syncthreads();
    #pragma unroll
    for (int k = 0; k < BK; ++k) {
      float a[8];
      *(float4*)&a[0] = *(const float4*)&hs[k][ty * 8];
      *(float4*)&a[4] = *(const float4*)&hs[k][ty * 8 + 4];
      #pragma unroll
      for (int g = 0; g < 4; ++g) {
        float4 bv = *(const float4*)&wsb[g][k][tx * 4];
        #pragma unroll
        for (int mm = 0; mm < 8; ++mm) {
          acc[g][mm][0] += a[mm] * bv.x;
          acc[g][mm][1] += a[mm] * bv.y;
          acc[g][mm][2] += a[mm] * bv.z;
          acc[g][mm][3] += a[mm] * bv.w;
        }
      }
    }
    __syncthreads();
  }

  // epilogue: add x-path table, LSTM cell, write c and h
  #pragma unroll
  for (int mm = 0; mm < 8; ++mm) {
    int b = b0 + ty * 8 + mm;
    int s = sel[b];
    const float* t = tbl + (size_t)s * FH;
    int j = j0 + tx * 4;
    float4 ti = *(const float4*)(t + j);
    float4 tf = *(const float4*)(t + H + j);
    float4 tg = *(const float4*)(t + 2*H + j);
    float4 to = *(const float4*)(t + 3*H + j);
    size_t off = (size_t)b * H + j;
    float4 cp = *(const float4*)(cbuf + off);
    float4 cn, hn;
    cn.x = sigf(acc[1][mm][0]+tf.x)*cp.x + sigf(acc[0][mm][0]+ti.x)*tanhf(acc[2][mm][0]+tg.x);
    cn.y = sigf(acc[1][mm][1]+tf.y)*cp.y + sigf(acc[0][mm][1]+ti.y)*tanhf(acc[2][mm][1]+tg.y);
    cn.z = sigf(acc[1][mm][2]+tf.z)*cp.z + sigf(acc[0][mm][2]+ti.z)*tanhf(acc[2][mm][2]+tg.z);
    cn.w = sigf(acc[1][mm][3]+tf.w)*cp.w + sigf(acc[0][mm][3]+ti.w)*tanhf(acc[2][mm][3]+tg.w);
    hn.x = sigf(acc[3][mm][0]+to.x)*tanhf(cn.x);
    hn.y = sigf(acc[3][mm][1]+to.y)*tanhf(cn.y);
    hn.z = sigf(acc[3][mm][2]+to.z)*tanhf(cn.z);
    hn.w = sigf(acc[3][mm][3]+to.w)*tanhf(cn.w);
    *(float4*)(cbuf + off) = cn;
    *(float4*)(hout + off) = hn;
  }
}

// ---------------- sampler: logits -> gumbel -> softmax -> argmax -> outputs ----------------
__global__ void sampler_kernel(const float* __restrict__ h,
                               const float* __restrict__ selW, const float* __restrict__ selb,
                               const float* __restrict__ gu,
                               float* __restrict__ val_out, float* __restrict__ wb_out,
                               float* __restrict__ p_out,
                               float v0, float v1, float v2,
                               int* __restrict__ sel) {
  int wave = threadIdx.x >> 6;
  int lane = threadIdx.x & 63;
  int b = blockIdx.x * 4 + wave;
  const float* hr = h + (size_t)b * H;
  float acc0 = 0, acc1 = 0, acc2 = 0;
  #pragma unroll
  for (int ch = 0; ch < 4; ++ch) {
    int k = ch * 256 + lane * 4;
    float4 hv = *(const float4*)(hr + k);
    float4 w0 = *(const float4*)(selW + k);
    float4 w1 = *(const float4*)(selW + H + k);
    float4 w2 = *(const float4*)(selW + 2*H + k);
    acc0 += hv.x*w0.x + hv.y*w0.y + hv.z*w0.z + hv.w*w0.w;
    acc1 += hv.x*w1.x + hv.y*w1.y + hv.z*w1.z + hv.w*w1.w;
    acc2 += hv.x*w2.x + hv.y*w2.y + hv.z*w2.z + hv.w*w2.w;
  }
  #pragma unroll
  for (int off = 32; off > 0; off >>= 1) {
    acc0 += __shfl_xor(acc0, off);
    acc1 += __shfl_xor(acc1, off);
    acc2 += __shfl_xor(acc2, off);
  }
  if (lane == 0) {
    float y0 = acc0 + selb[0] - logf(-logf(gu[(size_t)b*3 + 0]));
    float y1 = acc1 + selb[1] - logf(-logf(gu[(size_t)b*3 + 1]));
    float y2 = acc2 + selb[2] - logf(-logf(gu[(size_t)b*3 + 2]));
    int s = 0;
    float best = y0;
    if (y1 > best) { s = 1; best = y1; }
    if (y2 > best) { s = 2; best = y2; }
    float e0 = expf(y0 - best), e1 = expf(y1 - best), e2 = expf(y2 - best);
    float inv = 1.0f / (e0 + e1 + e2);
    float p0 = e0 * inv, p1 = e1 * inv, p2 = e2 * inv;
    val_out[b] = (s == 0) ? v0 : ((s == 1) ? v1 : v2);
    wb_out[(size_t)b*3 + 0] = (((s==0)?1.0f:0.0f) - p0) + p0;
    wb_out[(size_t)b*3 + 1] = (((s==1)?1.0f:0.0f) - p1) + p1;
    wb_out[(size_t)b*3 + 2] = (((s==2)?1.0f:0.0f) - p2) + p2;
    p_out[(size_t)b*3 + 0] = p0;
    p_out[(size_t)b*3 + 1] = p1;
    p_out[(size_t)b*3 + 2] = p2;
    sel[b] = s;
  }
}

}  // namespace

extern "C" void kernel_launch(void* const* d_in, const int* in_sizes, int n_in,
                              void* d_out, int out_size, void* d_ws, size_t ws_size,
                              hipStream_t stream) {
  (void)in_sizes; (void)n_in; (void)out_size; (void)ws_size;
  const float* constraints = (const float*)d_in[0];
  const int*   sid         = (const int*)d_in[1];
  const float* gumbel      = (const float*)d_in[2];
  const float* cond_emb    = (const float*)d_in[3];
  const float* sc_emb      = (const float*)d_in[4];
  const float* depth_emb   = (const float*)d_in[5];
  const float* ratio_emb   = (const float*)d_in[6];
  const float* ks_emb      = (const float*)d_in[7];
  const float* W_ih        = (const float*)d_in[8];
  const float* b_ih        = (const float*)d_in[9];
  const float* W_hh        = (const float*)d_in[10];
  const float* b_hh        = (const float*)d_in[11];
  const float* depth_W     = (const float*)d_in[12];
  const float* depth_b     = (const float*)d_in[13];
  const float* width_W     = (const float*)d_in[14];
  const float* width_b     = (const float*)d_in[15];
  const float* ks_W        = (const float*)d_in[16];
  const float* ks_b        = (const float*)d_in[17];

  float* out = (float*)d_out;
  float* ws  = (float*)d_ws;
  float* hA    = ws;                         // B*H
  float* hB    = hA + (size_t)B * H;         // B*H
  float* cb    = hB + (size_t)B * H;         // B*H
  float* tblD  = cb + (size_t)B * H;         // 3*FH
  float* tblR  = tblD + 3 * FH;
  float* tblK  = tblR + 3 * FH;
  float* condp = tblK + 3 * FH;              // 5*FH
  float* base0 = condp + 5 * FH;             // FH
  int*   sel   = (int*)(base0 + FH);         // B ints

  precompute_kernel<<<FH / 256, 256, 0, stream>>>(
      W_ih, b_ih, b_hh, depth_emb, ratio_emb, ks_emb, cond_emb, sc_emb, sid,
      tblD, tblR, tblK, condp, base0);
  step0_kernel<<<(B * H) / 256, 256, 0, stream>>>(constraints, condp, base0, hA, cb);

  const float* selW_arr[3] = {depth_W, width_W, ks_W};
  const float* selb_arr[3] = {depth_b, width_b, ks_b};
  const float vals[3][3]   = {{2.f,3.f,4.f},{3.f,4.f,6.f},{3.f,5.f,7.f}};
  float* tbl_arr[3]        = {tblD, tblR, tblK};

  // output layout (floats): depths 5B | ratios 20B | kss 20B | dwbs 15B | dprobs 15B
  //                         | rwbs 60B | rprobs 60B | kwbs 60B | kprobs 60B
  const size_t DEPTHS = 0,          RATIOS = (size_t)5*B,   KSS    = (size_t)25*B,
               DWBS   = (size_t)45*B, DPROBS = (size_t)60*B,
               RWBS   = (size_t)75*B, RPROBS = (size_t)135*B,
               KWBS   = (size_t)195*B, KPROBS = (size_t)255*B;

  float* hcur = hA;
  float* hnxt = hB;
  for (int t = 0; t < NSTEPS; ++t) {
    if (t > 0) {
      int pt = (t - 1) % 9;                       // previous sampler's type picks the embed table
      int ptype = (pt == 0) ? 0 : ((pt & 1) ? 1 : 2);
      lstm_step<<<dim3(H / BN, B / BM), 256, 0, stream>>>(hcur, hnxt, cb, W_hh, tbl_arr[ptype], sel);
      float* tmp = hcur; hcur = hnxt; hnxt = tmp;
    }
    int r = t % 9, u = t / 9;
    int ty, row;
    float *valp, *wbp, *pp;
    if (r == 0)      { ty = 0; row = u;
      valp = out + DEPTHS + (size_t)row*B; wbp = out + DWBS + (size_t)row*B*3; pp = out + DPROBS + (size_t)row*B*3; }
    else if (r & 1)  { ty = 1; row = u*4 + (r-1)/2;
      valp = out + RATIOS + (size_t)row*B; wbp = out + RWBS + (size_t)row*B*3; pp = out + RPROBS + (size_t)row*B*3; }
    else             { ty = 2; row = u*4 + (r-2)/2;
      valp = out + KSS + (size_t)row*B;    wbp = out + KWBS + (size_t)row*B*3; pp = out + KPROBS + (size_t)row*B*3; }
    sampler_kernel<<<B / 4, 256, 0, stream>>>(
        hcur, selW_arr[ty], selb_arr[ty], gumbel + (size_t)t * B * 3,
        valp, wbp, pp, vals[ty][0], vals[ty][1], vals[ty][2], sel);
  }
}

// Round 2
// 5708.320 us; speedup vs baseline: 3.2232x; 3.2232x over previous
//
#include <hip/hip_runtime.h>
#include <cmath>

namespace {

typedef _Float16 f16;
typedef f16 f16x8 __attribute__((ext_vector_type(8)));
typedef f16 f16x4 __attribute__((ext_vector_type(4)));
typedef float f32x4 __attribute__((ext_vector_type(4)));

constexpr int B  = 4096;
constexpr int H  = 1024;
constexpr int FH = 4 * H;   // 4096
constexpr int NSTEPS = 45;
constexpr float INVS = 1.0f / 2048.0f;

__device__ __forceinline__ float sigf(float x) { return 1.0f / (1.0f + expf(-x)); }

struct HL { f16 h, l; };
// safe split: hi is 0 or a normal f16; lo = f16((a-hi)*2048) (normal or negligible)
__device__ __forceinline__ HL split16(float a) {
  float ah = (float)(f16)a;
  if (fabsf(a) < 6.1035156e-5f) ah = 0.0f;   // would-be-subnormal hi -> push all into lo
  HL r; r.h = (f16)ah; r.l = (f16)((a - ah) * 2048.0f); return r;
}

__device__ __forceinline__ void async16(f16* lds_dst, const f16* gsrc) {
  __builtin_amdgcn_global_load_lds(
      (const __attribute__((address_space(1))) void*)gsrc,
      (__attribute__((address_space(3))) void*)lds_dst, 16, 0, 0);
}

// ---------------- one-time: split W_hh into f16 hi/lo ----------------
__global__ void convertW_kernel(const float* __restrict__ W,
                                f16* __restrict__ Whi, f16* __restrict__ Wlo) {
  size_t i = ((size_t)blockIdx.x * 256 + threadIdx.x) * 4;
  float4 v = *(const float4*)(W + i);
  HL a = split16(v.x), b = split16(v.y), c = split16(v.z), d = split16(v.w);
  f16x4 hi = {a.h, b.h, c.h, d.h};
  f16x4 lo = {a.l, b.l, c.l, d.l};
  *(f16x4*)(Whi + i) = hi;
  *(f16x4*)(Wlo + i) = lo;
}

// ---------------- one-time precompute of x-path tables (fp32) ----------------
__global__ void precompute_kernel(
    const float* __restrict__ W_ih, const float* __restrict__ b_ih, const float* __restrict__ b_hh,
    const float* __restrict__ depth_emb, const float* __restrict__ ratio_emb, const float* __restrict__ ks_emb,
    const float* __restrict__ cond_emb, const float* __restrict__ sc_emb, const int* __restrict__ sid_p,
    float* __restrict__ tblD, float* __restrict__ tblR, float* __restrict__ tblK,
    float* __restrict__ condp, float* __restrict__ base0) {
  int j = blockIdx.x * blockDim.x + threadIdx.x;
  if (j >= FH) return;
  const float* wr = W_ih + (size_t)j * H;
  float aD0=0,aD1=0,aD2=0,aR0=0,aR1=0,aR2=0,aK0=0,aK1=0,aK2=0;
  for (int k = 0; k < H; ++k) {
    float w = wr[k];
    aD0 += depth_emb[k]       * w;
    aD1 += depth_emb[H + k]   * w;
    aD2 += depth_emb[2*H + k] * w;
    aR0 += ratio_emb[k]       * w;
    aR1 += ratio_emb[H + k]   * w;
    aR2 += ratio_emb[2*H + k] * w;
    aK0 += ks_emb[k]          * w;
    aK1 += ks_emb[H + k]      * w;
    aK2 += ks_emb[2*H + k]    * w;
  }
  int sid = sid_p[0];
  constexpr int HH = H / 2;
  float a0=0,a1=0,a2=0,a3=0,a4=0,aS=0;
  for (int k = 0; k < HH; ++k) {
    float w = wr[k];
    a0 += cond_emb[0*HH + k] * w;
    a1 += cond_emb[1*HH + k] * w;
    a2 += cond_emb[2*HH + k] * w;
    a3 += cond_emb[3*HH + k] * w;
    a4 += cond_emb[4*HH + k] * w;
    aS += sc_emb[sid*HH + k] * wr[HH + k];
  }
  float bias = b_ih[j] + b_hh[j];
  tblD[0*FH+j]=aD0+bias; tblD[1*FH+j]=aD1+bias; tblD[2*FH+j]=aD2+bias;
  tblR[0*FH+j]=aR0+bias; tblR[1*FH+j]=aR1+bias; tblR[2*FH+j]=aR2+bias;
  tblK[0*FH+j]=aK0+bias; tblK[1*FH+j]=aK1+bias; tblK[2*FH+j]=aK2+bias;
  condp[0*FH+j]=a0; condp[1*FH+j]=a1; condp[2*FH+j]=a2; condp[3*FH+j]=a3; condp[4*FH+j]=a4;
  base0[j] = aS + bias;
}

// ---------------- step 0: h=c=0 ----------------
__global__ void step0_kernel(const float* __restrict__ constraints,
                             const float* __restrict__ condp, const float* __restrict__ base0,
                             f16* __restrict__ hhi, f16* __restrict__ hlo, float* __restrict__ c) {
  int idx = blockIdx.x * blockDim.x + threadIdx.x;   // b*H + j
  int b = idx >> 10;
  int j = idx & (H - 1);
  float cv = constraints[b];
  int i0 = 0;
  if (cv >= 12.5f) i0 = 1;
  if (cv >= 15.0f) i0 = 2;
  if (cv >= 17.5f) i0 = 3;
  float right = 10.0f + 2.5f * (float)(i0 + 1);
  float w = (right - cv) / 2.5f;
  const float* c0 = condp + (size_t)i0 * FH;
  const float* c1 = c0 + FH;
  float iw = 1.0f - w;
  float xi = w*c0[j]       + iw*c1[j]       + base0[j];
  float xg = w*c0[2*H+j]   + iw*c1[2*H+j]   + base0[2*H+j];
  float xo = w*c0[3*H+j]   + iw*c1[3*H+j]   + base0[3*H+j];
  float cn = sigf(xi) * tanhf(xg);
  float hn = sigf(xo) * tanhf(cn);
  c[idx] = cn;
  HL s = split16(hn);
  hhi[idx] = s.h; hlo[idx] = s.l;
}

// ---------------- MFMA LSTM step ----------------
// Block: 128 b-rows x 32 j-cols x 4 gates. 4 waves.
// B-tile rows r(0..127): gate = r>>5, j = j0 + (r&31).
// Wave w: m-half = (w>>1)*64, j-16block = (w&1)*16.
// Frag (mf, nf): A rows (w>>1)*64+mf*16+l15, B rows nf*32+(w&1)*16+l15 -> gate nf.
__global__ __launch_bounds__(256, 2) void lstm_step_mfma(
    const f16* __restrict__ hhi, const f16* __restrict__ hlo,
    f16* __restrict__ nhhi, f16* __restrict__ nhlo,
    float* __restrict__ cbuf,
    const f16* __restrict__ Whi, const f16* __restrict__ Wlo,
    const float* __restrict__ tbl, const int* __restrict__ sel) {
  __shared__ __align__(16) f16 lds[4 * 4096];   // AH | AL | BH | BL, each [128 rows][32 k]
  f16* AHs = lds;
  f16* ALs = lds + 4096;
  f16* BHs = lds + 8192;
  f16* BLs = lds + 12288;

  const int tid  = threadIdx.x;
  const int lane = tid & 63;
  const int w    = tid >> 6;
  const int l15  = lane & 15;
  const int kph  = lane >> 4;           // nominal 16B chunk 0..3
  const int b0   = blockIdx.y * 128;
  const int j0   = blockIdx.x * 32;

  f32x4 accH[4][4] = {};
  f32x4 accL[4][4] = {};

  const int srow = tid >> 2;            // staging row (+p*64)
  const int cph  = tid & 3;             // staging physical chunk

  for (int kt = 0; kt < H; kt += 32) {
    #pragma unroll
    for (int p = 0; p < 2; ++p) {
      int r  = p * 64 + srow;
      int cl = cph ^ (r & 3);                       // pre-swizzled global source (m173)
      int dst = p * 2048 + w * 512;                 // wave-uniform; HW adds lane*16B
      const size_t asrc = (size_t)(b0 + r) * H + kt + cl * 8;
      async16(AHs + dst, hhi + asrc);
      async16(ALs + dst, hlo + asrc);
      int wrow = ((r >> 5) << 10) + j0 + (r & 31);  // permuted W row: gate-major
      const size_t bsrc = (size_t)wrow * H + kt + cl * 8;
      async16(BHs + dst, Whi + bsrc);
      async16(BLs + dst, Wlo + bsrc);
    }
    __syncthreads();

    f16x8 ah[4], al[4], bh[4], bl[4];
    #pragma unroll
    for (int mf = 0; mf < 4; ++mf) {
      int R = (w >> 1) * 64 + mf * 16 + l15;
      int off = R * 32 + (kph ^ (R & 3)) * 8;
      ah[mf] = *(const f16x8*)(AHs + off);
      al[mf] = *(const f16x8*)(ALs + off);
    }
    #pragma unroll
    for (int nf = 0; nf < 4; ++nf) {
      int R = nf * 32 + (w & 1) * 16 + l15;
      int off = R * 32 + (kph ^ (R & 3)) * 8;
      bh[nf] = *(const f16x8*)(BHs + off);
      bl[nf] = *(const f16x8*)(BLs + off);
    }
    #pragma unroll
    for (int mf = 0; mf < 4; ++mf) {
      #pragma unroll
      for (int nf = 0; nf < 4; ++nf) {
        accH[mf][nf] = __builtin_amdgcn_mfma_f32_16x16x32_f16(ah[mf], bh[nf], accH[mf][nf], 0, 0, 0);
        accL[mf][nf] = __builtin_amdgcn_mfma_f32_16x16x32_f16(ah[mf], bl[nf], accL[mf][nf], 0, 0, 0);
        accL[mf][nf] = __builtin_amdgcn_mfma_f32_16x16x32_f16(al[mf], bh[nf], accL[mf][nf], 0, 0, 0);
      }
    }
    __syncthreads();
  }

  // epilogue: gates -> LSTM cell -> c, h(hi/lo)
  #pragma unroll
  for (int mf = 0; mf < 4; ++mf) {
    #pragma unroll
    for (int r = 0; r < 4; ++r) {
      int b = b0 + (w >> 1) * 64 + mf * 16 + (lane >> 4) * 4 + r;
      int j = j0 + (w & 1) * 16 + l15;
      int s = sel[b];
      const float* t = tbl + (size_t)s * FH + j;
      float gi = accH[mf][0][r] + accL[mf][0][r] * INVS + t[0];
      float gf = accH[mf][1][r] + accL[mf][1][r] * INVS + t[H];
      float gg = accH[mf][2][r] + accL[mf][2][r] * INVS + t[2*H];
      float go = accH[mf][3][r] + accL[mf][3][r] * INVS + t[3*H];
      size_t off = (size_t)b * H + j;
      float cp = cbuf[off];
      float cn = sigf(gf) * cp + sigf(gi) * tanhf(gg);
      float hn = sigf(go) * tanhf(cn);
      cbuf[off] = cn;
      HL sp = split16(hn);
      nhhi[off] = sp.h;
      nhlo[off] = sp.l;
    }
  }
}

// ---------------- sampler ----------------
__global__ void sampler_kernel(const f16* __restrict__ hhi, const f16* __restrict__ hlo,
                               const float* __restrict__ selW, const float* __restrict__ selb,
                               const float* __restrict__ gu,
                               float* __restrict__ val_out, float* __restrict__ wb_out,
                               float* __restrict__ p_out,
                               float v0, float v1, float v2,
                               int* __restrict__ sel) {
  int wave = threadIdx.x >> 6;
  int lane = threadIdx.x & 63;
  int b = blockIdx.x * 4 + wave;
  const f16* hh = hhi + (size_t)b * H;
  const f16* hl = hlo + (size_t)b * H;
  float acc0 = 0, acc1 = 0, acc2 = 0;
  #pragma unroll
  for (int ch = 0; ch < 4; ++ch) {
    int k = ch * 256 + lane * 4;
    f16x4 vh = *(const f16x4*)(hh + k);
    f16x4 vl = *(const f16x4*)(hl + k);
    float x0 = (float)vh[0] + (float)vl[0] * INVS;
    float x1 = (float)vh[1] + (float)vl[1] * INVS;
    float x2 = (float)vh[2] + (float)vl[2] * INVS;
    float x3 = (float)vh[3] + (float)vl[3] * INVS;
    float4 w0 = *(const float4*)(selW + k);
    float4 w1 = *(const float4*)(selW + H + k);
    float4 w2 = *(const float4*)(selW + 2*H + k);
    acc0 += x0*w0.x + x1*w0.y + x2*w0.z + x3*w0.w;
    acc1 += x0*w1.x + x1*w1.y + x2*w1.z + x3*w1.w;
    acc2 += x0*w2.x + x1*w2.y + x2*w2.z + x3*w2.w;
  }
  #pragma unroll
  for (int off = 32; off > 0; off >>= 1) {
    acc0 += __shfl_xor(acc0, off);
    acc1 += __shfl_xor(acc1, off);
    acc2 += __shfl_xor(acc2, off);
  }
  if (lane == 0) {
    float y0 = acc0 + selb[0] - logf(-logf(gu[(size_t)b*3 + 0]));
    float y1 = acc1 + selb[1] - logf(-logf(gu[(size_t)b*3 + 1]));
    float y2 = acc2 + selb[2] - logf(-logf(gu[(size_t)b*3 + 2]));
    int s = 0;
    float best = y0;
    if (y1 > best) { s = 1; best = y1; }
    if (y2 > best) { s = 2; best = y2; }
    float e0 = expf(y0 - best), e1 = expf(y1 - best), e2 = expf(y2 - best);
    float inv = 1.0f / (e0 + e1 + e2);
    float p0 = e0 * inv, p1 = e1 * inv, p2 = e2 * inv;
    val_out[b] = (s == 0) ? v0 : ((s == 1) ? v1 : v2);
    wb_out[(size_t)b*3 + 0] = (s == 0) ? 1.0f : 0.0f;
    wb_out[(size_t)b*3 + 1] = (s == 1) ? 1.0f : 0.0f;
    wb_out[(size_t)b*3 + 2] = (s == 2) ? 1.0f : 0.0f;
    p_out[(size_t)b*3 + 0] = p0;
    p_out[(size_t)b*3 + 1] = p1;
    p_out[(size_t)b*3 + 2] = p2;
    sel[b] = s;
  }
}

}  // namespace

extern "C" void kernel_launch(void* const* d_in, const int* in_sizes, int n_in,
                              void* d_out, int out_size, void* d_ws, size_t ws_size,
                              hipStream_t stream) {
  (void)in_sizes; (void)n_in; (void)out_size; (void)ws_size;
  const float* constraints = (const float*)d_in[0];
  const int*   sid         = (const int*)d_in[1];
  const float* gumbel      = (const float*)d_in[2];
  const float* cond_emb    = (const float*)d_in[3];
  const float* sc_emb      = (const float*)d_in[4];
  const float* depth_emb   = (const float*)d_in[5];
  const float* ratio_emb   = (const float*)d_in[6];
  const float* ks_emb      = (const float*)d_in[7];
  const float* W_ih        = (const float*)d_in[8];
  const float* W_hh        = (const float*)d_in[10];
  const float* b_ih        = (const float*)d_in[9];
  const float* b_hh        = (const float*)d_in[11];
  const float* depth_W     = (const float*)d_in[12];
  const float* depth_b     = (const float*)d_in[13];
  const float* width_W     = (const float*)d_in[14];
  const float* width_b     = (const float*)d_in[15];
  const float* ks_W        = (const float*)d_in[16];
  const float* ks_b        = (const float*)d_in[17];

  float* out = (float*)d_out;
  float* ws  = (float*)d_ws;

  float* cb    = ws;                                 // B*H f32 (16MB)
  f16*   W16hi = (f16*)(cb + (size_t)B * H);         // FH*H f16 (8MB)
  f16*   W16lo = W16hi + (size_t)FH * H;             // 8MB
  f16*   hhiA  = W16lo + (size_t)FH * H;             // B*H f16 (8MB)
  f16*   hloA  = hhiA + (size_t)B * H;
  f16*   hhiB  = hloA + (size_t)B * H;
  f16*   hloB  = hhiB + (size_t)B * H;
  float* tblD  = (float*)(hloB + (size_t)B * H);     // 3*FH f32
  float* tblR  = tblD + 3 * FH;
  float* tblK  = tblR + 3 * FH;
  float* condp = tblK + 3 * FH;                      // 5*FH
  float* base0 = condp + 5 * FH;                     // FH
  int*   sel   = (int*)(base0 + FH);                 // B

  convertW_kernel<<<(FH * H / 4) / 256, 256, 0, stream>>>(W_hh, W16hi, W16lo);
  precompute_kernel<<<FH / 256, 256, 0, stream>>>(
      W_ih, b_ih, b_hh, depth_emb, ratio_emb, ks_emb, cond_emb, sc_emb, sid,
      tblD, tblR, tblK, condp, base0);
  step0_kernel<<<(B * H) / 256, 256, 0, stream>>>(constraints, condp, base0, hhiA, hloA, cb);

  const float* selW_arr[3] = {depth_W, width_W, ks_W};
  const float* selb_arr[3] = {depth_b, width_b, ks_b};
  const float vals[3][3]   = {{2.f,3.f,4.f},{3.f,4.f,6.f},{3.f,5.f,7.f}};
  float* tbl_arr[3]        = {tblD, tblR, tblK};

  const size_t DEPTHS = 0,            RATIOS = (size_t)5*B,   KSS    = (size_t)25*B,
               DWBS   = (size_t)45*B, DPROBS = (size_t)60*B,
               RWBS   = (size_t)75*B, RPROBS = (size_t)135*B,
               KWBS   = (size_t)195*B, KPROBS = (size_t)255*B;

  f16* hhi_cur = hhiA; f16* hlo_cur = hloA;
  f16* hhi_nxt = hhiB; f16* hlo_nxt = hloB;
  for (int t = 0; t < NSTEPS; ++t) {
    if (t > 0) {
      int pt = (t - 1) % 9;
      int ptype = (pt == 0) ? 0 : ((pt & 1) ? 1 : 2);
      lstm_step_mfma<<<dim3(H / 32, B / 128), 256, 0, stream>>>(
          hhi_cur, hlo_cur, hhi_nxt, hlo_nxt, cb, W16hi, W16lo, tbl_arr[ptype], sel);
      f16* th = hhi_cur; hhi_cur = hhi_nxt; hhi_nxt = th;
      f16* tl = hlo_cur; hlo_cur = hlo_nxt; hlo_nxt = tl;
    }
    int r = t % 9, u = t / 9;
    int ty, row;
    float *valp, *wbp, *pp;
    if (r == 0)      { ty = 0; row = u;
      valp = out + DEPTHS + (size_t)row*B; wbp = out + DWBS + (size_t)row*B*3; pp = out + DPROBS + (size_t)row*B*3; }
    else if (r & 1)  { ty = 1; row = u*4 + (r-1)/2;
      valp = out + RATIOS + (size_t)row*B; wbp = out + RWBS + (size_t)row*B*3; pp = out + RPROBS + (size_t)row*B*3; }
    else             { ty = 2; row = u*4 + (r-2)/2;
      valp = out + KSS + (size_t)row*B;    wbp = out + KWBS + (size_t)row*B*3; pp = out + KPROBS + (size_t)row*B*3; }
    sampler_kernel<<<B / 4, 256, 0, stream>>>(
        hhi_cur, hlo_cur, selW_arr[ty], selb_arr[ty], gumbel + (size_t)t * B * 3,
        valp, wbp, pp, vals[ty][0], vals[ty][1], vals[ty][2], sel);
  }
}

// Round 3
// 5207.220 us; speedup vs baseline: 3.5334x; 1.0962x over previous
//
#include <hip/hip_runtime.h>
#include <cmath>

namespace {

typedef _Float16 f16;
typedef f16 f16x8 __attribute__((ext_vector_type(8)));
typedef f16 f16x4 __attribute__((ext_vector_type(4)));
typedef float f32x4 __attribute__((ext_vector_type(4)));

constexpr int B  = 4096;
constexpr int H  = 1024;
constexpr int FH = 4 * H;   // 4096
constexpr int NSTEPS = 45;
constexpr float INVS = 1.0f / 2048.0f;

__device__ __forceinline__ float sigf(float x) { return 1.0f / (1.0f + expf(-x)); }

struct HL { f16 h, l; };
// safe split: hi is 0 or a normal f16; lo = f16((a-hi)*2048) (normal or negligible)
__device__ __forceinline__ HL split16(float a) {
  float ah = (float)(f16)a;
  if (fabsf(a) < 6.1035156e-5f) ah = 0.0f;   // would-be-subnormal hi -> push all into lo
  HL r; r.h = (f16)ah; r.l = (f16)((a - ah) * 2048.0f); return r;
}

__device__ __forceinline__ void async16(f16* lds_dst, const f16* gsrc) {
  __builtin_amdgcn_global_load_lds(
      (const __attribute__((address_space(1))) void*)gsrc,
      (__attribute__((address_space(3))) void*)lds_dst, 16, 0, 0);
}

// ---------------- one-time: split W_hh into f16 hi/lo ----------------
__global__ void convertW_kernel(const float* __restrict__ W,
                                f16* __restrict__ Whi, f16* __restrict__ Wlo) {
  size_t i = ((size_t)blockIdx.x * 256 + threadIdx.x) * 4;
  float4 v = *(const float4*)(W + i);
  HL a = split16(v.x), b = split16(v.y), c = split16(v.z), d = split16(v.w);
  f16x4 hi = {a.h, b.h, c.h, d.h};
  f16x4 lo = {a.l, b.l, c.l, d.l};
  *(f16x4*)(Whi + i) = hi;
  *(f16x4*)(Wlo + i) = lo;
}

// ---------------- one-time precompute of x-path tables (wave-parallel) ----------------
// One wave per output row j: lane-parallel over K, shuffle reduce.
__global__ void precompute_kernel(
    const float* __restrict__ W_ih, const float* __restrict__ b_ih, const float* __restrict__ b_hh,
    const float* __restrict__ depth_emb, const float* __restrict__ ratio_emb, const float* __restrict__ ks_emb,
    const float* __restrict__ cond_emb, const float* __restrict__ sc_emb, const int* __restrict__ sid_p,
    float* __restrict__ tblD, float* __restrict__ tblR, float* __restrict__ tblK,
    float* __restrict__ condp, float* __restrict__ base0) {
  const int w4   = threadIdx.x >> 6;
  const int lane = threadIdx.x & 63;
  const int j    = blockIdx.x * 4 + w4;
  const float* wr = W_ih + (size_t)j * H;
  const int k = lane * 16;
  float4 wv0 = *(const float4*)(wr + k);
  float4 wv1 = *(const float4*)(wr + k + 4);
  float4 wv2 = *(const float4*)(wr + k + 8);
  float4 wv3 = *(const float4*)(wr + k + 12);

  auto dot = [&](const float* e) -> float {
    float4 e0 = *(const float4*)(e);
    float4 e1 = *(const float4*)(e + 4);
    float4 e2 = *(const float4*)(e + 8);
    float4 e3 = *(const float4*)(e + 12);
    return e0.x*wv0.x + e0.y*wv0.y + e0.z*wv0.z + e0.w*wv0.w
         + e1.x*wv1.x + e1.y*wv1.y + e1.z*wv1.z + e1.w*wv1.w
         + e2.x*wv2.x + e2.y*wv2.y + e2.z*wv2.z + e2.w*wv2.w
         + e3.x*wv3.x + e3.y*wv3.y + e3.z*wv3.z + e3.w*wv3.w;
  };

  float a[15];
  a[0] = dot(depth_emb + k);       a[1] = dot(depth_emb + H + k);   a[2] = dot(depth_emb + 2*H + k);
  a[3] = dot(ratio_emb + k);       a[4] = dot(ratio_emb + H + k);   a[5] = dot(ratio_emb + 2*H + k);
  a[6] = dot(ks_emb + k);          a[7] = dot(ks_emb + H + k);      a[8] = dot(ks_emb + 2*H + k);
  a[9] = a[10] = a[11] = a[12] = a[13] = a[14] = 0.0f;
  constexpr int HH = H / 2;
  int sid = sid_p[0];
  if (lane < 32) {
    a[9]  = dot(cond_emb + 0*HH + k);
    a[10] = dot(cond_emb + 1*HH + k);
    a[11] = dot(cond_emb + 2*HH + k);
    a[12] = dot(cond_emb + 3*HH + k);
    a[13] = dot(cond_emb + 4*HH + k);
  } else {
    a[14] = dot(sc_emb + sid*HH + (k - HH));   // pairs with wr[HH + kk]
  }
  #pragma unroll
  for (int i = 0; i < 15; ++i) {
    #pragma unroll
    for (int off = 32; off > 0; off >>= 1) a[i] += __shfl_xor(a[i], off);
  }
  if (lane == 0) {
    float bias = b_ih[j] + b_hh[j];
    tblD[0*FH+j]=a[0]+bias; tblD[1*FH+j]=a[1]+bias; tblD[2*FH+j]=a[2]+bias;
    tblR[0*FH+j]=a[3]+bias; tblR[1*FH+j]=a[4]+bias; tblR[2*FH+j]=a[5]+bias;
    tblK[0*FH+j]=a[6]+bias; tblK[1*FH+j]=a[7]+bias; tblK[2*FH+j]=a[8]+bias;
    condp[0*FH+j]=a[9]; condp[1*FH+j]=a[10]; condp[2*FH+j]=a[11];
    condp[3*FH+j]=a[12]; condp[4*FH+j]=a[13];
    base0[j] = a[14] + bias;
  }
}

// ---------------- step 0: h=c=0 ----------------
__global__ void step0_kernel(const float* __restrict__ constraints,
                             const float* __restrict__ condp, const float* __restrict__ base0,
                             f16* __restrict__ hhi, f16* __restrict__ hlo, float* __restrict__ c) {
  int idx = blockIdx.x * blockDim.x + threadIdx.x;   // b*H + j
  int b = idx >> 10;
  int j = idx & (H - 1);
  float cv = constraints[b];
  int i0 = 0;
  if (cv >= 12.5f) i0 = 1;
  if (cv >= 15.0f) i0 = 2;
  if (cv >= 17.5f) i0 = 3;
  float right = 10.0f + 2.5f * (float)(i0 + 1);
  float w = (right - cv) / 2.5f;
  const float* c0 = condp + (size_t)i0 * FH;
  const float* c1 = c0 + FH;
  float iw = 1.0f - w;
  float xi = w*c0[j]       + iw*c1[j]       + base0[j];
  float xg = w*c0[2*H+j]   + iw*c1[2*H+j]   + base0[2*H+j];
  float xo = w*c0[3*H+j]   + iw*c1[3*H+j]   + base0[3*H+j];
  float cn = sigf(xi) * tanhf(xg);
  float hn = sigf(xo) * tanhf(cn);
  c[idx] = cn;
  HL s = split16(hn);
  hhi[idx] = s.h; hlo[idx] = s.l;
}

// ---------------- MFMA LSTM step, 256x128 tile, 8 waves, dbuf 2-phase ----------------
// Tile: 256 b-rows x (4 gates x 32 j). Wave w: wm=w>>1 (64-row b-slice), wn=w&1 (16-col j-slice).
// LDS buf layout (f16 elems): AH[0,8192) AL[8192,16384) BH[16384,20480) BL[20480,24576)
// A/B rows stored [row][32 k] with 16B chunk swizzle: phys = kq ^ (R&3) ^ ((R>>2)&3).
constexpr int BUFE = 24576;

__device__ __forceinline__ void stage_tile(
    f16* buf, const f16* hhi, const f16* hlo,
    const f16* Whi, const f16* Wlo,
    int b0, int j0, int kt, int tid, int w) {
  int rs = tid >> 2;          // 0..127
  int cs = tid & 3;
  #pragma unroll
  for (int p = 0; p < 2; ++p) {
    int r  = p * 128 + rs;
    int cl = cs ^ (r & 3) ^ ((r >> 2) & 3);
    size_t src = (size_t)(b0 + r) * H + kt + cl * 8;
    f16* dstA = buf + p * 4096 + w * 512;      // wave-uniform; HW adds lane*16B
    async16(dstA, hhi + src);
    async16(dstA + 8192, hlo + src);
  }
  {
    int r  = rs;
    int cl = cs ^ (r & 3) ^ ((r >> 2) & 3);
    int wrow = ((r >> 5) << 10) + j0 + (r & 31);   // gate-major permuted W row
    size_t src = (size_t)wrow * H + kt + cl * 8;
    f16* dstB = buf + 16384 + w * 512;
    async16(dstB, Whi + src);
    async16(dstB + 4096, Wlo + src);
  }
}

__global__ __launch_bounds__(512, 2) void lstm_step_mfma(
    const f16* __restrict__ hhi, const f16* __restrict__ hlo,
    f16* __restrict__ nhhi, f16* __restrict__ nhlo,
    float* __restrict__ cbuf,
    const f16* __restrict__ Whi, const f16* __restrict__ Wlo,
    const float* __restrict__ tbl, const int* __restrict__ sel) {
  __shared__ __align__(16) f16 lds[2 * BUFE];   // 96 KB

  const int tid  = threadIdx.x;
  const int lane = tid & 63;
  const int w    = tid >> 6;
  const int wm   = w >> 1, wn = w & 1;
  const int l15  = lane & 15;
  const int kq   = lane >> 4;

  // XCD-clustered tile assignment: each XCD owns 4 j-blocks x all 16 b-blocks,
  // so its W working set (2 MB) stays in its private L2.
  const int L   = blockIdx.x;          // 0..511, XCD ~ L%8 (round-robin dispatch)
  const int xcd = L & 7, seq = L >> 3;
  const int jb  = (xcd << 2) + (seq & 3);
  const int bb  = seq >> 2;
  const int b0  = bb << 8;
  const int j0  = jb << 5;

  f32x4 accH[4][4] = {};
  f32x4 accL[4][4] = {};

  stage_tile(lds, hhi, hlo, Whi, Wlo, b0, j0, 0, tid, w);
  __syncthreads();

  int cur = 0;
  for (int kt = 0; kt < 32; ++kt) {
    if (kt < 31)
      stage_tile(lds + (cur ^ 1) * BUFE, hhi, hlo, Whi, Wlo, b0, j0, (kt + 1) * 32, tid, w);

    const f16* bufc = lds + cur * BUFE;
    f16x8 ah[4], al[4], bh[4], bl[4];
    #pragma unroll
    for (int mf = 0; mf < 4; ++mf) {
      int R = wm * 64 + mf * 16 + l15;
      int c = kq ^ (R & 3) ^ ((R >> 2) & 3);
      int off = R * 32 + c * 8;
      ah[mf] = *(const f16x8*)(bufc + off);
      al[mf] = *(const f16x8*)(bufc + 8192 + off);
    }
    #pragma unroll
    for (int nf = 0; nf < 4; ++nf) {
      int R = nf * 32 + wn * 16 + l15;
      int c = kq ^ (R & 3) ^ ((R >> 2) & 3);
      int off = R * 32 + c * 8;
      bh[nf] = *(const f16x8*)(bufc + 16384 + off);
      bl[nf] = *(const f16x8*)(bufc + 20480 + off);
    }
    #pragma unroll
    for (int mf = 0; mf < 4; ++mf) {
      #pragma unroll
      for (int nf = 0; nf < 4; ++nf) {
        accH[mf][nf] = __builtin_amdgcn_mfma_f32_16x16x32_f16(ah[mf], bh[nf], accH[mf][nf], 0, 0, 0);
        accL[mf][nf] = __builtin_amdgcn_mfma_f32_16x16x32_f16(ah[mf], bl[nf], accL[mf][nf], 0, 0, 0);
        accL[mf][nf] = __builtin_amdgcn_mfma_f32_16x16x32_f16(al[mf], bh[nf], accL[mf][nf], 0, 0, 0);
      }
    }
    __syncthreads();
    cur ^= 1;
  }

  // epilogue: gates -> LSTM cell -> c, h(hi/lo)
  const int j = j0 + wn * 16 + l15;
  #pragma unroll
  for (int mf = 0; mf < 4; ++mf) {
    #pragma unroll
    for (int r = 0; r < 4; ++r) {
      int b = b0 + wm * 64 + mf * 16 + kq * 4 + r;
      int s = sel[b];
      const float* t = tbl + (size_t)s * FH + j;
      float gi = accH[mf][0][r] + accL[mf][0][r] * INVS + t[0];
      float gf = accH[mf][1][r] + accL[mf][1][r] * INVS + t[H];
      float gg = accH[mf][2][r] + accL[mf][2][r] * INVS + t[2*H];
      float go = accH[mf][3][r] + accL[mf][3][r] * INVS + t[3*H];
      size_t off = (size_t)b * H + j;
      float cp = cbuf[off];
      float cn = sigf(gf) * cp + sigf(gi) * tanhf(gg);
      float hn = sigf(go) * tanhf(cn);
      cbuf[off] = cn;
      HL sp = split16(hn);
      nhhi[off] = sp.h;
      nhlo[off] = sp.l;
    }
  }
}

// ---------------- sampler ----------------
__global__ void sampler_kernel(const f16* __restrict__ hhi, const f16* __restrict__ hlo,
                               const float* __restrict__ selW, const float* __restrict__ selb,
                               const float* __restrict__ gu,
                               float* __restrict__ val_out, float* __restrict__ wb_out,
                               float* __restrict__ p_out,
                               float v0, float v1, float v2,
                               int* __restrict__ sel) {
  int wave = threadIdx.x >> 6;
  int lane = threadIdx.x & 63;
  int b = blockIdx.x * 4 + wave;
  const f16* hh = hhi + (size_t)b * H;
  const f16* hl = hlo + (size_t)b * H;
  float acc0 = 0, acc1 = 0, acc2 = 0;
  #pragma unroll
  for (int ch = 0; ch < 4; ++ch) {
    int k = ch * 256 + lane * 4;
    f16x4 vh = *(const f16x4*)(hh + k);
    f16x4 vl = *(const f16x4*)(hl + k);
    float x0 = (float)vh[0] + (float)vl[0] * INVS;
    float x1 = (float)vh[1] + (float)vl[1] * INVS;
    float x2 = (float)vh[2] + (float)vl[2] * INVS;
    float x3 = (float)vh[3] + (float)vl[3] * INVS;
    float4 w0 = *(const float4*)(selW + k);
    float4 w1 = *(const float4*)(selW + H + k);
    float4 w2 = *(const float4*)(selW + 2*H + k);
    acc0 += x0*w0.x + x1*w0.y + x2*w0.z + x3*w0.w;
    acc1 += x0*w1.x + x1*w1.y + x2*w1.z + x3*w1.w;
    acc2 += x0*w2.x + x1*w2.y + x2*w2.z + x3*w2.w;
  }
  #pragma unroll
  for (int off = 32; off > 0; off >>= 1) {
    acc0 += __shfl_xor(acc0, off);
    acc1 += __shfl_xor(acc1, off);
    acc2 += __shfl_xor(acc2, off);
  }
  if (lane == 0) {
    float y0 = acc0 + selb[0] - logf(-logf(gu[(size_t)b*3 + 0]));
    float y1 = acc1 + selb[1] - logf(-logf(gu[(size_t)b*3 + 1]));
    float y2 = acc2 + selb[2] - logf(-logf(gu[(size_t)b*3 + 2]));
    int s = 0;
    float best = y0;
    if (y1 > best) { s = 1; best = y1; }
    if (y2 > best) { s = 2; best = y2; }
    float e0 = expf(y0 - best), e1 = expf(y1 - best), e2 = expf(y2 - best);
    float inv = 1.0f / (e0 + e1 + e2);
    float p0 = e0 * inv, p1 = e1 * inv, p2 = e2 * inv;
    val_out[b] = (s == 0) ? v0 : ((s == 1) ? v1 : v2);
    wb_out[(size_t)b*3 + 0] = (s == 0) ? 1.0f : 0.0f;
    wb_out[(size_t)b*3 + 1] = (s == 1) ? 1.0f : 0.0f;
    wb_out[(size_t)b*3 + 2] = (s == 2) ? 1.0f : 0.0f;
    p_out[(size_t)b*3 + 0] = p0;
    p_out[(size_t)b*3 + 1] = p1;
    p_out[(size_t)b*3 + 2] = p2;
    sel[b] = s;
  }
}

}  // namespace

extern "C" void kernel_launch(void* const* d_in, const int* in_sizes, int n_in,
                              void* d_out, int out_size, void* d_ws, size_t ws_size,
                              hipStream_t stream) {
  (void)in_sizes; (void)n_in; (void)out_size; (void)ws_size;
  const float* constraints = (const float*)d_in[0];
  const int*   sid         = (const int*)d_in[1];
  const float* gumbel      = (const float*)d_in[2];
  const float* cond_emb    = (const float*)d_in[3];
  const float* sc_emb      = (const float*)d_in[4];
  const float* depth_emb   = (const float*)d_in[5];
  const float* ratio_emb   = (const float*)d_in[6];
  const float* ks_emb      = (const float*)d_in[7];
  const float* W_ih        = (const float*)d_in[8];
  const float* b_ih        = (const float*)d_in[9];
  const float* W_hh        = (const float*)d_in[10];
  const float* b_hh        = (const float*)d_in[11];
  const float* depth_W     = (const float*)d_in[12];
  const float* depth_b     = (const float*)d_in[13];
  const float* width_W     = (const float*)d_in[14];
  const float* width_b     = (const float*)d_in[15];
  const float* ks_W        = (const float*)d_in[16];
  const float* ks_b        = (const float*)d_in[17];

  float* out = (float*)d_out;
  float* ws  = (float*)d_ws;

  float* cb    = ws;                                 // B*H f32 (16MB)
  f16*   W16hi = (f16*)(cb + (size_t)B * H);         // FH*H f16 (8MB)
  f16*   W16lo = W16hi + (size_t)FH * H;             // 8MB
  f16*   hhiA  = W16lo + (size_t)FH * H;             // B*H f16
  f16*   hloA  = hhiA + (size_t)B * H;
  f16*   hhiB  = hloA + (size_t)B * H;
  f16*   hloB  = hhiB + (size_t)B * H;
  float* tblD  = (float*)(hloB + (size_t)B * H);     // 3*FH f32
  float* tblR  = tblD + 3 * FH;
  float* tblK  = tblR + 3 * FH;
  float* condp = tblK + 3 * FH;                      // 5*FH
  float* base0 = condp + 5 * FH;                     // FH
  int*   sel   = (int*)(base0 + FH);                 // B

  convertW_kernel<<<(FH * H / 4) / 256, 256, 0, stream>>>(W_hh, W16hi, W16lo);
  precompute_kernel<<<FH / 4, 256, 0, stream>>>(
      W_ih, b_ih, b_hh, depth_emb, ratio_emb, ks_emb, cond_emb, sc_emb, sid,
      tblD, tblR, tblK, condp, base0);
  step0_kernel<<<(B * H) / 256, 256, 0, stream>>>(constraints, condp, base0, hhiA, hloA, cb);

  const float* selW_arr[3] = {depth_W, width_W, ks_W};
  const float* selb_arr[3] = {depth_b, width_b, ks_b};
  const float vals[3][3]   = {{2.f,3.f,4.f},{3.f,4.f,6.f},{3.f,5.f,7.f}};
  float* tbl_arr[3]        = {tblD, tblR, tblK};

  const size_t DEPTHS = 0,            RATIOS = (size_t)5*B,   KSS    = (size_t)25*B,
               DWBS   = (size_t)45*B, DPROBS = (size_t)60*B,
               RWBS   = (size_t)75*B, RPROBS = (size_t)135*B,
               KWBS   = (size_t)195*B, KPROBS = (size_t)255*B;

  f16* hhi_cur = hhiA; f16* hlo_cur = hloA;
  f16* hhi_nxt = hhiB; f16* hlo_nxt = hloB;
  for (int t = 0; t < NSTEPS; ++t) {
    if (t > 0) {
      int pt = (t - 1) % 9;
      int ptype = (pt == 0) ? 0 : ((pt & 1) ? 1 : 2);
      lstm_step_mfma<<<512, 512, 0, stream>>>(
          hhi_cur, hlo_cur, hhi_nxt, hlo_nxt, cb, W16hi, W16lo, tbl_arr[ptype], sel);
      f16* th = hhi_cur; hhi_cur = hhi_nxt; hhi_nxt = th;
      f16* tl = hlo_cur; hlo_cur = hlo_nxt; hlo_nxt = tl;
    }
    int r = t % 9, u = t / 9;
    int ty, row;
    float *valp, *wbp, *pp;
    if (r == 0)      { ty = 0; row = u;
      valp = out + DEPTHS + (size_t)row*B; wbp = out + DWBS + (size_t)row*B*3; pp = out + DPROBS + (size_t)row*B*3; }
    else if (r & 1)  { ty = 1; row = u*4 + (r-1)/2;
      valp = out + RATIOS + (size_t)row*B; wbp = out + RWBS + (size_t)row*B*3; pp = out + RPROBS + (size_t)row*B*3; }
    else             { ty = 2; row = u*4 + (r-2)/2;
      valp = out + KSS + (size_t)row*B;    wbp = out + KWBS + (size_t)row*B*3; pp = out + KPROBS + (size_t)row*B*3; }
    sampler_kernel<<<B / 4, 256, 0, stream>>>(
        hhi_cur, hlo_cur, selW_arr[ty], selb_arr[ty], gumbel + (size_t)t * B * 3,
        valp, wbp, pp, vals[ty][0], vals[ty][1], vals[ty][2], sel);
  }
}